// Round 5
// baseline (181.781 us; speedup 1.0000x reference)
//
#include <hip/hip_runtime.h>
#include <hip/hip_bf16.h>

// LoRA-factored 3x3 conv. out fp32. Input dtypes runtime-detected.
// x: [16,128,56,56], A: [256,16], B: [16,1152] -> out: [16,256,56,56]
// R9: R8's HB=4 + 1024thr balance kept, but the 96-reg accumulator spill
// (R8: WRITE +7.6MB scratch, VGPR=64) is fixed by the x-shuffle scheme:
// ONE acc set acc[4][8] (32 regs); horizontal taps come from ds_bpermute'd
// x (12 shuffles/channel) instead of 3 accumulator sets. Recombine epilogue
// gone. amdgpu_waves_per_eu(4,4) pins 1 block/CU so the allocator gets the
// full 128-VGPR budget (R8's 64-VGPR heuristic locked out). B in SGPRs
// (R7 proved LDS-B is LDS-pipe-bound). Grid 14x16=224 <= 256 CUs: single
// round, no tail.

#define Bn 16
#define Cc 128
#define Hh 56
#define Ww 56
#define Ll (Hh * Ww)      // 3136
#define Rr 16
#define Oo 256
#define KF (Cc * 9)       // 1152
#define HB 4              // output rows per block

__device__ __forceinline__ float bf16_bits(unsigned short u) {
    return __uint_as_float(((unsigned)u) << 16);
}

template<bool BF>
__device__ __forceinline__ float ld(const void* __restrict__ p, unsigned i) {
    if constexpr (BF) return bf16_bits(((const unsigned short*)p)[i]);
    else              return ((const float*)p)[i];
}

// bf16-packed: bits14..7 of each dword = a bf16 exponent (~[96,144]) -> 32/32.
// fp32: uniform mantissa bits -> ~6/32. Threshold 20. (Proven R3.)
__device__ __forceinline__ bool detect_bf16(const void* __restrict__ p) {
    const unsigned* w = (const unsigned*)p;
    int c = 0;
#pragma unroll
    for (int i = 0; i < 32; ++i) {
        const unsigned e = (w[i] >> 7) & 0xFFu;
        c += (e >= 96u && e <= 144u) ? 1 : 0;
    }
    return c >= 20;
}

// ---- prep: Bt[k][r] = B[r][k] as fp32 (k = c*9+i), Afp[o][r] = A[o][r] fp32.
__global__ __launch_bounds__(256) void prep_kernel(
    const void* __restrict__ A, const void* __restrict__ Bm,
    float* __restrict__ Bt, float* __restrict__ Afp)
{
    const bool ab = detect_bf16(A);
    const bool bb = detect_bf16(Bm);
    const int i = blockIdx.x * 256 + threadIdx.x;
    if (i < KF * Rr) {
        const int k = i >> 4, r = i & 15;
        Bt[i] = bb ? bf16_bits(((const unsigned short*)Bm)[r * KF + k])
                   : ((const float*)Bm)[r * KF + k];
    }
    if (i < Oo * Rr) {
        Afp[i] = ab ? bf16_bits(((const unsigned short*)A)[i])
                    : ((const float*)A)[i];
    }
}

// One channel-iteration: consume XBUF (center values) into xc, build left/
// right tap values via lane shuffles (masked at w=0 / w=55), prefetch channel
// CC+2 into XBUF, FMA against B (wave-uniform -> SGPR s_loads). Each B float
// feeds HB=4 FMAs; single accumulator set.
#define CONV_BODY(CC, XBUF)                                                  \
    {                                                                        \
        float xc[HB + 2], xl[HB + 2], xr[HB + 2];                            \
        _Pragma("unroll")                                                    \
        for (int rr = 0; rr < HB + 2; ++rr) {                                \
            xc[rr] = XBUF[rr];                                               \
            const float lv = __shfl(xc[rr], lane - 1);                       \
            const float rv = __shfl(xc[rr], lane + 1);                       \
            xl[rr] = wl ? lv : 0.f;                                          \
            xr[rr] = wr ? rv : 0.f;                                          \
        }                                                                    \
        const int ccn = ((CC) + 2 < 16) ? (CC) + 2 : (CC);                   \
        const unsigned coffn = (unsigned)(ccn * Ll);                         \
        _Pragma("unroll")                                                    \
        for (int rr = 0; rr < HB + 2; ++rr) {                                \
            const float v = ld<XB>(x, rowu[rr] + coffn + (unsigned)wcl);     \
            XBUF[rr] = hv[rr] ? v : 0.f;                                     \
        }                                                                    \
        const float* bt = btb + (size_t)((CC) * 9) * Rr;                     \
        _Pragma("unroll")                                                    \
        for (int dh = 0; dh < 3; ++dh) {                                     \
            _Pragma("unroll")                                                \
            for (int j = 0; j < 8; ++j) {                                    \
                const float b0 = bt[(dh * 3 + 0) * Rr + j]; /* SGPR */       \
                const float b1 = bt[(dh * 3 + 1) * Rr + j];                  \
                const float b2 = bt[(dh * 3 + 2) * Rr + j];                  \
                _Pragma("unroll")                                            \
                for (int row = 0; row < HB; ++row)                           \
                    acc[row][j] += b0 * xl[row + dh]                         \
                                 + b1 * xc[row + dh]                         \
                                 + b2 * xr[row + dh];                        \
            }                                                                \
        }                                                                    \
    }

// ---- main: one block = (b, rows h0..h0+3). 16 waves = 8 ch-slices x 2 rank-halves.
template<bool XB>
__device__ __forceinline__ void main_body(
    const void* __restrict__ x,
    const float* __restrict__ Bt,
    const float* __restrict__ Afp,
    float* __restrict__ out,
    float (* __restrict__ part)[Rr][64],   // [8][16][64]  (per-row reuse)
    float (* __restrict__ tmp2)[17])       // [64][17]     (per-row reuse)
{
    const int tid  = threadIdx.x;
    const int lane = tid & 63;                                  // w coordinate
    const int wv   = __builtin_amdgcn_readfirstlane(tid >> 6);  // wave 0..15 (SGPR)
    const int cs   = wv & 7;    // channel slice: channels cs*16 .. +16
    const int rh   = wv >> 3;   // rank half: ranks rh*8 .. +8
    const int h0   = blockIdx.x * HB;
    const int b    = blockIdx.y;
    const int w    = lane;
    const bool wok = (w < Ww);
    const int  wcl = wok ? w : (Ww - 1);   // clamp lanes 56..63 (garbage, masked)
    const bool wl  = (w > 0);              // left-neighbor tap valid
    const bool wr  = (w < Ww - 1);         // right-neighbor tap valid

    // single accumulator set: acc[row][rank] (32 VGPRs)
    float acc[HB][8];
#pragma unroll
    for (int row = 0; row < HB; ++row)
#pragma unroll
        for (int j = 0; j < 8; ++j) acc[row][j] = 0.f;

    const unsigned xbase = (unsigned)(b * Cc * Ll + (cs * 16) * Ll);
    const float* btb = Bt + (size_t)(cs * 16 * 9) * Rr + rh * 8;

    // rows needed: h0-1 .. h0+HB. Uniform bases (SGPR); per-lane offset = wcl.
    unsigned rowu[HB + 2];
    bool     hv[HB + 2];
#pragma unroll
    for (int rr = 0; rr < HB + 2; ++rr) {
        const int hh  = h0 - 1 + rr;
        hv[rr] = (hh >= 0) & (hh < Hh);
        const int hcl = hv[rr] ? hh : (hh < 0 ? 0 : Hh - 1);
        rowu[rr] = xbase + (unsigned)(hcl * Ww);
    }

    // ---- main loop over 16 channels, 2-deep x register double-buffer.
    float xbA[HB + 2], xbB[HB + 2];
#pragma unroll
    for (int rr = 0; rr < HB + 2; ++rr) {
        const float v0 = ld<XB>(x, rowu[rr] + (unsigned)wcl);
        xbA[rr] = hv[rr] ? v0 : 0.f;
        const float v1 = ld<XB>(x, rowu[rr] + (unsigned)Ll + (unsigned)wcl);
        xbB[rr] = hv[rr] ? v1 : 0.f;
    }
    for (int t = 0; t < 8; ++t) {
        CONV_BODY(2 * t,     xbA)
        CONV_BODY(2 * t + 1, xbB)
    }

    // ---- per-row epilogue: cross-wave reduce -> stage 2. (No recombine:
    // the x-shuffle scheme leaves acc final per (row, rank, w).)
    const size_t obase = (size_t)b * Oo * Ll + (size_t)(h0 * Ww) + (size_t)w;
#pragma unroll
    for (int row = 0; row < HB; ++row) {
#pragma unroll
        for (int j = 0; j < 8; ++j) part[cs][rh * 8 + j][lane] = acc[row][j];
        __syncthreads();

        // cross-wave reduction: 8 channel-slices -> tmp2[px][r]
        {
            const int r  = tid >> 6;    // 0..15 (1024 threads)
            const int px = tid & 63;
            float s = 0.f;
#pragma unroll
            for (int s8 = 0; s8 < 8; ++s8) s += part[s8][r][px];
            tmp2[px][r] = s;            // stride 17 -> conflict-free
        }
        __syncthreads();

        // stage 2: wave wv emits output channels wv*16 .. +16 for this row.
        float tv[Rr];
#pragma unroll
        for (int r = 0; r < Rr; ++r) tv[r] = tmp2[lane][r];

#pragma unroll
        for (int j = 0; j < 16; ++j) {
            const int o = wv * 16 + j;
            const float* Ao = Afp + (size_t)o * Rr;   // uniform -> s_load
            float s = 0.f;
#pragma unroll
            for (int r = 0; r < Rr; ++r) s += Ao[r] * tv[r];
            if (wok) out[obase + (size_t)o * Ll + (size_t)(row * Ww)] = s;
        }
        __syncthreads();   // part/tmp2 reused next row
    }
}

__global__ __attribute__((amdgpu_waves_per_eu(4, 4))) __launch_bounds__(1024)
void fused_big(
    const void* __restrict__ x,
    const float* __restrict__ Bt,
    const float* __restrict__ Afp,
    float* __restrict__ out)
{
    __shared__ float part[8][Rr][64];   // 32 KB (per-row reuse)
    __shared__ float tmp2[64][17];      // 4.3 KB
    if (detect_bf16(x)) main_body<true >(x, Bt, Afp, out, part, tmp2);
    else                main_body<false>(x, Bt, Afp, out, part, tmp2);
}

// ---- fallback (ws too small): slow but correct, no workspace.
__global__ __launch_bounds__(256) void fused_fallback(
    const void* __restrict__ x, const void* __restrict__ A,
    const void* __restrict__ Bm, float* __restrict__ out)
{
    const bool xb = detect_bf16(x);
    const bool ab = detect_bf16(A);
    const bool bb = detect_bf16(Bm);
    const int gid = blockIdx.x * 256 + threadIdx.x;
    const int b = gid / Ll;
    const int l = gid - b * Ll;
    const int h = l / Ww, w = l - h * Ww;
    float acc[Rr];
#pragma unroll
    for (int r = 0; r < Rr; ++r) acc[r] = 0.f;
    const size_t xbase = (size_t)b * Cc * Ll;
    for (int c = 0; c < Cc; ++c) {
        const size_t xc = xbase + (size_t)c * Ll;
        float xv[9];
#pragma unroll
        for (int dh = 0; dh < 3; ++dh) {
            const int hh = h + dh - 1;
            const bool hok = (hh >= 0) & (hh < Hh);
#pragma unroll
            for (int dw = 0; dw < 3; ++dw) {
                const int ww = w + dw - 1;
                const bool ok = hok & (ww >= 0) & (ww < Ww);
                const size_t idx = xc + (size_t)(hh * Ww + ww);
                xv[dh*3+dw] = ok ? (xb ? bf16_bits(((const unsigned short*)x)[idx])
                                       : ((const float*)x)[idx]) : 0.f;
            }
        }
#pragma unroll
        for (int r = 0; r < Rr; ++r) {
            const size_t bo = (size_t)r * KF + (size_t)c * 9;
            float s = acc[r];
#pragma unroll
            for (int i = 0; i < 9; ++i)
                s += (bb ? bf16_bits(((const unsigned short*)Bm)[bo+i])
                         : ((const float*)Bm)[bo+i]) * xv[i];
            acc[r] = s;
        }
    }
    const size_t obase = (size_t)b * Oo * Ll + (size_t)l;
    for (int o = 0; o < Oo; ++o) {
        float s = 0.f;
#pragma unroll
        for (int r = 0; r < Rr; ++r)
            s += (ab ? bf16_bits(((const unsigned short*)A)[o*Rr+r])
                     : ((const float*)A)[o*Rr+r]) * acc[r];
        out[obase + (size_t)o * Ll] = s;
    }
}

extern "C" void kernel_launch(void* const* d_in, const int* in_sizes, int n_in,
                              void* d_out, int out_size, void* d_ws, size_t ws_size,
                              hipStream_t stream) {
    const void* x  = d_in[0];
    const void* A  = d_in[1];
    const void* Bm = d_in[2];
    for (int i = 0; i < n_in && i < 3; ++i) {
        const int s = in_sizes[i];
        if      (s == Bn * Cc * Ll) x  = d_in[i];
        else if (s == Oo * Rr)      A  = d_in[i];
        else if (s == Rr * KF)      Bm = d_in[i];
    }
    float* out = (float*)d_out;

    const size_t need = (size_t)(KF * Rr + Oo * Rr) * sizeof(float);  // 90112 B
    if (ws_size >= need) {
        float* Bt  = (float*)d_ws;
        float* Afp = Bt + KF * Rr;
        prep_kernel<<<dim3((KF * Rr + 255) / 256), 256, 0, stream>>>(A, Bm, Bt, Afp);
        fused_big<<<dim3(Hh / HB, Bn), 1024, 0, stream>>>(x, Bt, Afp, out);
    } else {
        fused_fallback<<<dim3((Bn * Ll) / 256), 256, 0, stream>>>(x, A, Bm, out);
    }
}

// Round 6
// 117.800 us; speedup vs baseline: 1.5431x; 1.5431x over previous
//
#include <hip/hip_runtime.h>
#include <hip/hip_bf16.h>

// LoRA-factored 3x3 conv. out fp32. Input dtypes runtime-detected.
// x: [16,128,56,56], A: [256,16], B: [16,1152] -> out: [16,256,56,56]
// R10 = R6 (best: 48.9us, clean VGPR=40) + two surgical changes:
//  (1) nontemporal output stores: the 51MB write stream was thrashing LLC,
//      forcing x (12.8MB bf16) to re-fetch from HBM every dispatch
//      (FETCH = (HB+2)/HB * 12.8MB signature). nt stores keep x L3-resident.
//  (2) 4-deep x register prefetch (xb0..xb3): ~1200cy cover vs ~350cy L3 hit.
// Structure unchanged: 512 thr, 8 waves = 4 ch-slices x 2 rank-halves, HB=2,
// shifted-accumulator (3 acc sets, __shfl recombine once), B via SGPR s_load.
// R7 proved LDS-broadcast B is LDS-pipe-bound; R8/R9 proved HB=4 spills.

#define Bn 16
#define Cc 128
#define Hh 56
#define Ww 56
#define Ll (Hh * Ww)      // 3136
#define Rr 16
#define Oo 256
#define KF (Cc * 9)       // 1152
#define HB 2              // output rows per block

__device__ __forceinline__ float bf16_bits(unsigned short u) {
    return __uint_as_float(((unsigned)u) << 16);
}

template<bool BF>
__device__ __forceinline__ float ld(const void* __restrict__ p, unsigned i) {
    if constexpr (BF) return bf16_bits(((const unsigned short*)p)[i]);
    else              return ((const float*)p)[i];
}

// bf16-packed: bits14..7 of each dword = a bf16 exponent (~[96,144]) -> 32/32.
// fp32: uniform mantissa bits -> ~6/32. Threshold 20. (Proven R3.)
__device__ __forceinline__ bool detect_bf16(const void* __restrict__ p) {
    const unsigned* w = (const unsigned*)p;
    int c = 0;
#pragma unroll
    for (int i = 0; i < 32; ++i) {
        const unsigned e = (w[i] >> 7) & 0xFFu;
        c += (e >= 96u && e <= 144u) ? 1 : 0;
    }
    return c >= 20;
}

// ---- prep: Bt[k][r] = B[r][k] as fp32 (k = c*9+i), Afp[o][r] = A[o][r] fp32.
__global__ __launch_bounds__(256) void prep_kernel(
    const void* __restrict__ A, const void* __restrict__ Bm,
    float* __restrict__ Bt, float* __restrict__ Afp)
{
    const bool ab = detect_bf16(A);
    const bool bb = detect_bf16(Bm);
    const int i = blockIdx.x * 256 + threadIdx.x;
    if (i < KF * Rr) {
        const int k = i >> 4, r = i & 15;
        Bt[i] = bb ? bf16_bits(((const unsigned short*)Bm)[r * KF + k])
                   : ((const float*)Bm)[r * KF + k];
    }
    if (i < Oo * Rr) {
        Afp[i] = ab ? bf16_bits(((const unsigned short*)A)[i])
                    : ((const float*)A)[i];
    }
}

// One channel-iteration: consume XBUF into xv, prefetch channel CC+4 into
// XBUF (4-deep pipeline), FMA against B (wave-uniform -> SGPR s_loads).
#define CONV_BODY(CC, XBUF)                                                  \
    {                                                                        \
        float xv[HB + 2];                                                    \
        _Pragma("unroll")                                                    \
        for (int rr = 0; rr < HB + 2; ++rr) xv[rr] = XBUF[rr];               \
        const int ccn = ((CC) + 4 < 32) ? (CC) + 4 : (CC);                   \
        const unsigned coffn = (unsigned)(ccn * Ll);                         \
        _Pragma("unroll")                                                    \
        for (int rr = 0; rr < HB + 2; ++rr) {                                \
            const float v = ld<XB>(x, rowb[rr] + coffn);                     \
            XBUF[rr] = hv[rr] ? v : 0.f;                                     \
        }                                                                    \
        const float* bt = btb + (size_t)((CC) * 9) * Rr;                     \
        _Pragma("unroll")                                                    \
        for (int dh = 0; dh < 3; ++dh) {                                     \
            const float x0 = xv[dh];                                         \
            const float x1 = xv[dh + 1];                                     \
            _Pragma("unroll")                                                \
            for (int dw = 0; dw < 3; ++dw) {                                 \
                const float* bp = bt + (dh * 3 + dw) * Rr;                   \
                _Pragma("unroll")                                            \
                for (int j = 0; j < 8; ++j) {                                \
                    const float bv = bp[j];    /* SGPR (uniform) */          \
                    a[0][dw][j] += bv * x0;                                  \
                    a[1][dw][j] += bv * x1;                                  \
                }                                                            \
            }                                                                \
        }                                                                    \
    }

// ---- main: one block = (b, rows h0..h0+1). 8 waves = 4 ch-slices x 2 rank-halves.
template<bool XB>
__device__ __forceinline__ void main_body(
    const void* __restrict__ x,
    const float* __restrict__ Bt,
    const float* __restrict__ Afp,
    float* __restrict__ out,
    float (* __restrict__ part)[4][Rr][64],   // [HB][4][16][64]
    float (* __restrict__ tmp2)[64][17])      // [HB][64][17]
{
    const int tid  = threadIdx.x;
    const int lane = tid & 63;                                  // w coordinate
    const int wv   = __builtin_amdgcn_readfirstlane(tid >> 6);  // wave 0..7 (SGPR)
    const int cs   = wv & 3;    // channel slice: channels cs*32 .. +32
    const int rh   = wv >> 2;   // rank half: ranks rh*8 .. +8
    const int h0   = blockIdx.x * HB;
    const int b    = blockIdx.y;
    const int w    = lane;
    const bool wok = (w < Ww);
    const int  wcl = wok ? w : (Ww - 1);   // clamp lanes 56..63 (garbage, masked)

    // a[row][dw][rank]: shifted accumulators, recombined at the end.
    float a[HB][3][8];
#pragma unroll
    for (int row = 0; row < HB; ++row)
#pragma unroll
        for (int dw = 0; dw < 3; ++dw)
#pragma unroll
            for (int j = 0; j < 8; ++j) a[row][dw][j] = 0.f;

    const unsigned xbase = (unsigned)(b * Cc * Ll + (cs * 32) * Ll);
    const float* btb = Bt + (size_t)(cs * 32 * 9) * Rr + rh * 8;

    // rows needed: h0-1 .. h0+HB. validity is block-uniform -> SGPR selects.
    unsigned rowb[HB + 2];
    bool     hv[HB + 2];
#pragma unroll
    for (int rr = 0; rr < HB + 2; ++rr) {
        const int hh  = h0 - 1 + rr;
        hv[rr] = (hh >= 0) & (hh < Hh);
        const int hcl = hv[rr] ? hh : (hh < 0 ? 0 : Hh - 1);
        rowb[rr] = xbase + (unsigned)(hcl * Ww) + (unsigned)wcl;
    }

    // ---- main loop over 32 channels, 4-deep x register prefetch pipeline.
    float xb0[HB + 2], xb1[HB + 2], xb2[HB + 2], xb3[HB + 2];
#pragma unroll
    for (int rr = 0; rr < HB + 2; ++rr) {
        const float v0 = ld<XB>(x, rowb[rr]);
        xb0[rr] = hv[rr] ? v0 : 0.f;
        const float v1 = ld<XB>(x, rowb[rr] + (unsigned)Ll);
        xb1[rr] = hv[rr] ? v1 : 0.f;
        const float v2 = ld<XB>(x, rowb[rr] + (unsigned)(2 * Ll));
        xb2[rr] = hv[rr] ? v2 : 0.f;
        const float v3 = ld<XB>(x, rowb[rr] + (unsigned)(3 * Ll));
        xb3[rr] = hv[rr] ? v3 : 0.f;
    }
    for (int t = 0; t < 8; ++t) {
        CONV_BODY(4 * t,     xb0)
        CONV_BODY(4 * t + 1, xb1)
        CONV_BODY(4 * t + 2, xb2)
        CONV_BODY(4 * t + 3, xb3)
    }

    // horizontal recombine (once): out[w] = a1[w] + a0[w-1] + a2[w+1]
#pragma unroll
    for (int row = 0; row < HB; ++row)
#pragma unroll
    for (int j = 0; j < 8; ++j) {
        const float up = __shfl(a[row][0][j], w - 1);
        const float dn = __shfl(a[row][2][j], w + 1);
        float s = a[row][1][j];
        s += (w > 0)      ? up : 0.f;
        s += (w < Ww - 1) ? dn : 0.f;
        part[row][cs][rh * 8 + j][lane] = s;
    }
    __syncthreads();

    // cross-wave reduction: 4 channel-slices -> tmp2[row][px][r]
    {
        const int px = tid & 63;
        const int rr = (tid >> 6) & 7;   // 0..7
#pragma unroll
        for (int row = 0; row < HB; ++row)
#pragma unroll
        for (int t = 0; t < 2; ++t) {
            const int r = rr + t * 8;
            tmp2[row][px][r] = part[row][0][r][px] + part[row][1][r][px]
                             + part[row][2][r][px] + part[row][3][r][px];
        }
    }
    __syncthreads();

    // stage 2: wave wv emits output channels wv*32 .. +32, both rows.
    float tv[HB][Rr];
#pragma unroll
    for (int row = 0; row < HB; ++row)
#pragma unroll
        for (int r = 0; r < Rr; ++r) tv[row][r] = tmp2[row][lane][r];

    const size_t obase = (size_t)b * Oo * Ll + (size_t)(h0 * Ww) + (size_t)w;
#pragma unroll 4
    for (int j = 0; j < 32; ++j) {
        const int o = wv * 32 + j;
        const float* Ao = Afp + (size_t)o * Rr;   // uniform -> s_load
        float s0 = 0.f, s1 = 0.f;
#pragma unroll
        for (int r = 0; r < Rr; ++r) {
            const float av = Ao[r];
            s0 += av * tv[0][r];
            s1 += av * tv[1][r];
        }
        if (wok) {
            // nontemporal: out is write-once; keep it from evicting x in L2/L3
            __builtin_nontemporal_store(s0, &out[obase + (size_t)o * Ll]);
            __builtin_nontemporal_store(s1, &out[obase + (size_t)o * Ll + Ww]);
        }
    }
}

__global__ __launch_bounds__(512, 4) void fused_big(
    const void* __restrict__ x,
    const float* __restrict__ Bt,
    const float* __restrict__ Afp,
    float* __restrict__ out)
{
    __shared__ float part[HB][4][Rr][64];   // 32 KB
    __shared__ float tmp2[HB][64][17];      // 8.7 KB
    if (detect_bf16(x)) main_body<true >(x, Bt, Afp, out, part, tmp2);
    else                main_body<false>(x, Bt, Afp, out, part, tmp2);
}

// ---- fallback (ws too small): slow but correct, no workspace.
__global__ __launch_bounds__(256) void fused_fallback(
    const void* __restrict__ x, const void* __restrict__ A,
    const void* __restrict__ Bm, float* __restrict__ out)
{
    const bool xb = detect_bf16(x);
    const bool ab = detect_bf16(A);
    const bool bb = detect_bf16(Bm);
    const int gid = blockIdx.x * 256 + threadIdx.x;
    const int b = gid / Ll;
    const int l = gid - b * Ll;
    const int h = l / Ww, w = l - h * Ww;
    float acc[Rr];
#pragma unroll
    for (int r = 0; r < Rr; ++r) acc[r] = 0.f;
    const size_t xbase = (size_t)b * Cc * Ll;
    for (int c = 0; c < Cc; ++c) {
        const size_t xc = xbase + (size_t)c * Ll;
        float xv[9];
#pragma unroll
        for (int dh = 0; dh < 3; ++dh) {
            const int hh = h + dh - 1;
            const bool hok = (hh >= 0) & (hh < Hh);
#pragma unroll
            for (int dw = 0; dw < 3; ++dw) {
                const int ww = w + dw - 1;
                const bool ok = hok & (ww >= 0) & (ww < Ww);
                const size_t idx = xc + (size_t)(hh * Ww + ww);
                xv[dh*3+dw] = ok ? (xb ? bf16_bits(((const unsigned short*)x)[idx])
                                       : ((const float*)x)[idx]) : 0.f;
            }
        }
#pragma unroll
        for (int r = 0; r < Rr; ++r) {
            const size_t bo = (size_t)r * KF + (size_t)c * 9;
            float s = acc[r];
#pragma unroll
            for (int i = 0; i < 9; ++i)
                s += (bb ? bf16_bits(((const unsigned short*)Bm)[bo+i])
                         : ((const float*)Bm)[bo+i]) * xv[i];
            acc[r] = s;
        }
    }
    const size_t obase = (size_t)b * Oo * Ll + (size_t)l;
    for (int o = 0; o < Oo; ++o) {
        float s = 0.f;
#pragma unroll
        for (int r = 0; r < Rr; ++r)
            s += (ab ? bf16_bits(((const unsigned short*)A)[o*Rr+r])
                     : ((const float*)A)[o*Rr+r]) * acc[r];
        out[obase + (size_t)o * Ll] = s;
    }
}

extern "C" void kernel_launch(void* const* d_in, const int* in_sizes, int n_in,
                              void* d_out, int out_size, void* d_ws, size_t ws_size,
                              hipStream_t stream) {
    const void* x  = d_in[0];
    const void* A  = d_in[1];
    const void* Bm = d_in[2];
    for (int i = 0; i < n_in && i < 3; ++i) {
        const int s = in_sizes[i];
        if      (s == Bn * Cc * Ll) x  = d_in[i];
        else if (s == Oo * Rr)      A  = d_in[i];
        else if (s == Rr * KF)      Bm = d_in[i];
    }
    float* out = (float*)d_out;

    const size_t need = (size_t)(KF * Rr + Oo * Rr) * sizeof(float);  // 90112 B
    if (ws_size >= need) {
        float* Bt  = (float*)d_ws;
        float* Afp = Bt + KF * Rr;
        prep_kernel<<<dim3((KF * Rr + 255) / 256), 256, 0, stream>>>(A, Bm, Bt, Afp);
        fused_big<<<dim3(Hh / HB, Bn), 512, 0, stream>>>(x, Bt, Afp, out);
    } else {
        fused_fallback<<<dim3((Bn * Ll) / 256), 256, 0, stream>>>(x, A, Bm, out);
    }
}